// Round 2
// baseline (8064.198 us; speedup 1.0000x reference)
//
#include <hip/hip_runtime.h>

#define B_ 64
#define T_ 2048
#define F_ 8
#define H_ 128

typedef _Float16 v2h __attribute__((ext_vector_type(2)));

// pack two fp32 into one dword of two f16 (RTN via cast)
__device__ __forceinline__ unsigned pk2h(float lo, float hi) {
    v2h p;
    p[0] = (_Float16)lo;
    p[1] = (_Float16)hi;
    return __builtin_bit_cast(unsigned, p);
}

#if __has_builtin(__builtin_amdgcn_fdot2)
__device__ __forceinline__ float fdot2a(unsigned a, unsigned b, float c) {
    return __builtin_amdgcn_fdot2(__builtin_bit_cast(v2h, a),
                                  __builtin_bit_cast(v2h, b), c, false);
}
#else
__device__ __forceinline__ float fdot2a(unsigned a, unsigned b, float c) {
    v2h av = __builtin_bit_cast(v2h, a);
    v2h bv = __builtin_bit_cast(v2h, b);
    c += (float)av[0] * (float)bv[0];
    c += (float)av[1] * (float)bv[1];
    return c;
}
#endif

__device__ __forceinline__ float sigm(float x) {
    return 1.0f / (1.0f + __expf(-x));
}
__device__ __forceinline__ float tanh_f(float x) {
    float e = __expf(2.0f * x);
    return 1.0f - 2.0f / (e + 1.0f);
}

// In-quad lane exchanges via DPP quad_perm (VALU pipe, no LDS)
#if __has_builtin(__builtin_amdgcn_mov_dpp)
template <int CTRL>
__device__ __forceinline__ float qperm(float v) {
    int i = __builtin_bit_cast(int, v);
    i = __builtin_amdgcn_mov_dpp(i, CTRL, 0xF, 0xF, true);
    return __builtin_bit_cast(float, i);
}
__device__ __forceinline__ float lane_xor1(float v) { return qperm<0xB1>(v); } // [1,0,3,2]
__device__ __forceinline__ float lane_xor2(float v) { return qperm<0x4E>(v); } // [2,3,0,1]
#else
__device__ __forceinline__ float lane_xor1(float v) {
    int i = __builtin_amdgcn_ds_swizzle(__builtin_bit_cast(int, v), 0x041F);
    return __builtin_bit_cast(float, i);
}
__device__ __forceinline__ float lane_xor2(float v) {
    int i = __builtin_amdgcn_ds_swizzle(__builtin_bit_cast(int, v), 0x081F);
    return __builtin_bit_cast(float, i);
}
#endif

// Thread map (512 threads): tid = h_idx*4 + gslot
//   h_idx 0..127; gslot 0..3 -> gate order [i, g, f, o] (rows {0,2,1,3}*128 + h_idx).
// Each thread computes the FULL 128-elem dot for its gate row (196 weight dwords in regs).
// Cell update fully in-quad:
//   act lanes: 0:i 1:g 2:f 3:o
//   s1 = xor1(act): 0:g 1:i 2:o 3:f
//   p  = sub<2 ? act*s1 : (sub==2 ? act : s1)*c    -> lanes 01: i*g, lanes 23: f*c
//   c' = p + xor2(p)  == i*g + f*c (replicated in quad)
//   h  = o * tanh(c'); o = s1 on lane2, act on lane3; lane 2 writes h (f16) to LDS.
__global__ __launch_bounds__(512, 1)
void lstm2_pipe512_kernel(const float* __restrict__ x,
                          const float* __restrict__ wih0,
                          const float* __restrict__ whh0,
                          const float* __restrict__ bih0,
                          const float* __restrict__ bhh0,
                          const float* __restrict__ wih1,
                          const float* __restrict__ whh1,
                          const float* __restrict__ bih1,
                          const float* __restrict__ bhh1,
                          const float* __restrict__ wlin,
                          const float* __restrict__ blin,
                          float* __restrict__ out)
{
    __shared__ __align__(16) unsigned x_lds[T_ * F_ / 2];   // 32 KB packed f16 x
    __shared__ __align__(16) unsigned h0_p[2][H_ / 2];      // double-buffered h0 (f16 pairs)
    __shared__ __align__(16) unsigned h1_p[2][H_ / 2];      // double-buffered h1
    __shared__ __align__(16) unsigned wlin_p[512];          // w_lin packed f16 pairs
    __shared__ float blin_f[F_];

    const int tid   = threadIdx.x;
    const int b     = blockIdx.x;
    const int h_idx = tid >> 2;
    const int sub   = tid & 3;                          // gslot == quad lane
    const int grow  = (0x3120 >> (sub * 4)) & 0xF;      // {0,2,1,3}[sub]
    const int row   = grow * H_ + h_idx;                // gate row (PyTorch i,f,g,o layout)

    // ---- stage x[b] into LDS as packed f16 pairs ----
    const float4* xp = (const float4*)(x + (size_t)b * T_ * F_);
    #pragma unroll
    for (int i = 0; i < 8; ++i) {
        int idx = tid + i * 512;          // 4096 float4 total
        float4 v = xp[idx];
        x_lds[idx * 2 + 0] = pk2h(v.x, v.y);
        x_lds[idx * 2 + 1] = pk2h(v.z, v.w);
    }

    // ---- per-thread full-row weights -> VGPRs (196 packed dwords) ----
    unsigned rwih0[4];
    {
        const float4* p = (const float4*)(wih0 + (size_t)row * F_);
        float4 v0 = p[0], v1 = p[1];
        rwih0[0] = pk2h(v0.x, v0.y); rwih0[1] = pk2h(v0.z, v0.w);
        rwih0[2] = pk2h(v1.x, v1.y); rwih0[3] = pk2h(v1.z, v1.w);
    }
    unsigned rwhh0[64], rwih1[64], rwhh1[64];
    {
        const float4* p = (const float4*)(whh0 + (size_t)row * H_);
        #pragma unroll
        for (int i = 0; i < 32; ++i) {
            float4 v = p[i];
            rwhh0[i * 2 + 0] = pk2h(v.x, v.y);
            rwhh0[i * 2 + 1] = pk2h(v.z, v.w);
        }
    }
    {
        const float4* p = (const float4*)(wih1 + (size_t)row * H_);
        #pragma unroll
        for (int i = 0; i < 32; ++i) {
            float4 v = p[i];
            rwih1[i * 2 + 0] = pk2h(v.x, v.y);
            rwih1[i * 2 + 1] = pk2h(v.z, v.w);
        }
    }
    {
        const float4* p = (const float4*)(whh1 + (size_t)row * H_);
        #pragma unroll
        for (int i = 0; i < 32; ++i) {
            float4 v = p[i];
            rwhh1[i * 2 + 0] = pk2h(v.x, v.y);
            rwhh1[i * 2 + 1] = pk2h(v.z, v.w);
        }
    }
    const float bias0 = bih0[row] + bhh0[row];
    const float bias1 = bih1[row] + bhh1[row];

    // w_lin: [8][128] fp32 -> 512 packed pairs; pair p = f*64 + k covers h = 2k,2k+1
    {
        float2 v = ((const float2*)wlin)[tid];
        wlin_p[tid] = pk2h(v.x, v.y);
    }
    if (tid < F_) blin_f[tid] = blin[tid];
    if (tid < H_ / 2) {
        h0_p[0][tid] = 0u; h0_p[1][tid] = 0u;
        h1_p[0][tid] = 0u; h1_p[1][tid] = 0u;
    }
    __syncthreads();

    const bool is_g = (sub == 1);
    const bool lo2  = (sub < 2);
    float c0 = 0.0f, c1 = 0.0f;    // cell state, replicated across each quad

    // Pipelined: tick k does L0(t=k) || L1(t=k-1) || OUT(t=k-2). ONE barrier per tick.
    for (int k = 0; k <= T_ + 1; ++k) {
        const int rb = (k + 1) & 1;   // holds h0(k-1); write parity for h1(k-1)
        const int wb = k & 1;         // write parity for h0(k); holds h1(k-2)

        // ---------- layer 0: t = k ----------
        if (k < T_) {
            float aa = bias0, ab = 0.0f;
            uint4 xv = *(const uint4*)&x_lds[k * 4];
            aa = fdot2a(rwih0[0], xv.x, aa);
            ab = fdot2a(rwih0[1], xv.y, ab);
            aa = fdot2a(rwih0[2], xv.z, aa);
            ab = fdot2a(rwih0[3], xv.w, ab);
            const unsigned* hr = &h0_p[rb][0];
            #pragma unroll
            for (int j = 0; j < 16; ++j) {
                uint4 hv = *(const uint4*)&hr[j * 4];
                aa = fdot2a(rwhh0[j * 4 + 0], hv.x, aa);
                ab = fdot2a(rwhh0[j * 4 + 1], hv.y, ab);
                aa = fdot2a(rwhh0[j * 4 + 2], hv.z, aa);
                ab = fdot2a(rwhh0[j * 4 + 3], hv.w, ab);
            }
            float a = aa + ab;
            float xin = is_g ? 2.0f * a : a;
            float s   = sigm(xin);
            float act = is_g ? 2.0f * s - 1.0f : s;   // tanh via sigmoid, branch-free
            float s1  = lane_xor1(act);
            float p   = lo2 ? act * s1 : (sub == 2 ? act : s1) * c0;
            float cn  = p + lane_xor2(p);
            c0 = cn;
            float oval = (sub == 2) ? s1 : act;
            float h = oval * tanh_f(cn);
            if (sub == 2) ((_Float16*)&h0_p[wb][0])[h_idx] = (_Float16)h;
        }

        // ---------- layer 1: t = k-1 ----------
        if (k >= 1 && k <= T_) {
            float aa = bias1, ab = 0.0f, ba = 0.0f, bb = 0.0f;
            const unsigned* h0r = &h0_p[rb][0];   // h0(k-1)
            const unsigned* h1r = &h1_p[wb][0];   // h1(k-2)
            #pragma unroll
            for (int j = 0; j < 16; ++j) {
                uint4 hv = *(const uint4*)&h0r[j * 4];
                aa = fdot2a(rwih1[j * 4 + 0], hv.x, aa);
                ab = fdot2a(rwih1[j * 4 + 1], hv.y, ab);
                aa = fdot2a(rwih1[j * 4 + 2], hv.z, aa);
                ab = fdot2a(rwih1[j * 4 + 3], hv.w, ab);
            }
            #pragma unroll
            for (int j = 0; j < 16; ++j) {
                uint4 hv = *(const uint4*)&h1r[j * 4];
                ba = fdot2a(rwhh1[j * 4 + 0], hv.x, ba);
                bb = fdot2a(rwhh1[j * 4 + 1], hv.y, bb);
                ba = fdot2a(rwhh1[j * 4 + 2], hv.z, ba);
                bb = fdot2a(rwhh1[j * 4 + 3], hv.w, bb);
            }
            float a = (aa + ab) + (ba + bb);
            float xin = is_g ? 2.0f * a : a;
            float s   = sigm(xin);
            float act = is_g ? 2.0f * s - 1.0f : s;
            float s1  = lane_xor1(act);
            float p   = lo2 ? act * s1 : (sub == 2 ? act : s1) * c1;
            float cn  = p + lane_xor2(p);
            c1 = cn;
            float oval = (sub == 2) ? s1 : act;
            float h = oval * tanh_f(cn);
            if (sub == 2) ((_Float16*)&h1_p[rb][0])[h_idx] = (_Float16)h;   // h1(k-1)
        }

        // ---------- output linear: t = k-2 (wave 0 only) ----------
        if (k >= 2 && tid < 64) {
            int fo = tid >> 3;       // output feature 0..7
            int l  = tid & 7;        // 8 lanes per feature, 16 h-elems each
            const unsigned* hp = &h1_p[wb][0];   // h1(k-2)
            float a = 0.0f;
            #pragma unroll
            for (int jj = 0; jj < 8; ++jj) {
                a = fdot2a(wlin_p[fo * 64 + l * 8 + jj], hp[l * 8 + jj], a);
            }
            a += __shfl_down(a, 4, 8);
            a += __shfl_down(a, 2, 8);
            a += __shfl_down(a, 1, 8);
            if (l == 0) {
                out[((size_t)b * T_ + (k - 2)) * F_ + fo] = a + blin_f[fo];
            }
        }

        __syncthreads();
    }
}

extern "C" void kernel_launch(void* const* d_in, const int* in_sizes, int n_in,
                              void* d_out, int out_size, void* d_ws, size_t ws_size,
                              hipStream_t stream) {
    const float* x    = (const float*)d_in[0];
    const float* wih0 = (const float*)d_in[1];
    const float* whh0 = (const float*)d_in[2];
    const float* bih0 = (const float*)d_in[3];
    const float* bhh0 = (const float*)d_in[4];
    const float* wih1 = (const float*)d_in[5];
    const float* whh1 = (const float*)d_in[6];
    const float* bih1 = (const float*)d_in[7];
    const float* bhh1 = (const float*)d_in[8];
    const float* wlin = (const float*)d_in[9];
    const float* blin = (const float*)d_in[10];
    float* out = (float*)d_out;

    lstm2_pipe512_kernel<<<dim3(B_), dim3(512), 0, stream>>>(
        x, wih0, whh0, bih0, bhh0, wih1, whh1, bih1, bhh1, wlin, blin, out);
}

// Round 3
// 3203.249 us; speedup vs baseline: 2.5175x; 2.5175x over previous
//
#include <hip/hip_runtime.h>

#define B_ 64
#define T_ 2048
#define F_ 8
#define H_ 128

typedef _Float16 v2h __attribute__((ext_vector_type(2)));

// pack two fp32 into one dword of two f16 (RTN via cast)
__device__ __forceinline__ unsigned pk2h(float lo, float hi) {
    v2h p;
    p[0] = (_Float16)lo;
    p[1] = (_Float16)hi;
    return __builtin_bit_cast(unsigned, p);
}

#if __has_builtin(__builtin_amdgcn_fdot2)
__device__ __forceinline__ float fdot2a(unsigned a, unsigned b, float c) {
    return __builtin_amdgcn_fdot2(__builtin_bit_cast(v2h, a),
                                  __builtin_bit_cast(v2h, b), c, false);
}
#else
__device__ __forceinline__ float fdot2a(unsigned a, unsigned b, float c) {
    v2h av = __builtin_bit_cast(v2h, a);
    v2h bv = __builtin_bit_cast(v2h, b);
    c += (float)av[0] * (float)bv[0];
    c += (float)av[1] * (float)bv[1];
    return c;
}
#endif

__device__ __forceinline__ float sigm(float x) {
    return 1.0f / (1.0f + __expf(-x));
}
__device__ __forceinline__ float tanh_f(float x) {
    float e = __expf(2.0f * x);
    return 1.0f - 2.0f / (e + 1.0f);
}

// In-quad lane exchanges via DPP quad_perm (VALU pipe, no LDS)
#if __has_builtin(__builtin_amdgcn_mov_dpp)
template <int CTRL>
__device__ __forceinline__ float qperm(float v) {
    int i = __builtin_bit_cast(int, v);
    i = __builtin_amdgcn_mov_dpp(i, CTRL, 0xF, 0xF, true);
    return __builtin_bit_cast(float, i);
}
__device__ __forceinline__ float lane_xor1(float v) { return qperm<0xB1>(v); } // [1,0,3,2]
__device__ __forceinline__ float lane_xor2(float v) { return qperm<0x4E>(v); } // [2,3,0,1]
#else
__device__ __forceinline__ float lane_xor1(float v) {
    int i = __builtin_amdgcn_ds_swizzle(__builtin_bit_cast(int, v), 0x041F);
    return __builtin_bit_cast(float, i);
}
__device__ __forceinline__ float lane_xor2(float v) {
    int i = __builtin_amdgcn_ds_swizzle(__builtin_bit_cast(int, v), 0x081F);
    return __builtin_bit_cast(float, i);
}
#endif

// Thread map (512 threads): tid = h_idx*4 + sub
//   h_idx 0..127; sub 0..3 -> gate order [i, g, f, o] (rows {0,2,1,3}*128 + h_idx).
// Cell update fully in-quad (verified bit-identical vs gates[]-LDS version):
//   act lanes: 0:sig(i) 1:tanh(g) 2:sig(f) 3:sig(o)
//   s1 = xor1(act): 0:tanh(g) 1:sig(i) 2:sig(o) 3:sig(f)
//   p  = sub<2 ? act*s1 : (sub==2 ? act : s1)*c    -> lanes01: i*g, lanes23: f*c
//   c' = p + xor2(p)  == i*g + f*c (replicated in quad)
//   h  = sig(o) * tanh(c'); lane sub==2 (oval=s1) writes h (f16) to LDS.
//
// Tick structure (2 barriers/tick — barriers double as register-pressure fences;
// round-2 showed that a single merged region spills):
//   Phase A: L0 dots(t) + quad update + h0(t) write || wave0: OUT(t-1)
//   barrier
//   Phase B: L1 dots(t) (uses fresh h0(t)) + quad update + h1(t) write
//   barrier
__global__ __launch_bounds__(512, 2)
void lstm2_2bar_kernel(const float* __restrict__ x,
                       const float* __restrict__ wih0,
                       const float* __restrict__ whh0,
                       const float* __restrict__ bih0,
                       const float* __restrict__ bhh0,
                       const float* __restrict__ wih1,
                       const float* __restrict__ whh1,
                       const float* __restrict__ bih1,
                       const float* __restrict__ bhh1,
                       const float* __restrict__ wlin,
                       const float* __restrict__ blin,
                       float* __restrict__ out)
{
    __shared__ __align__(16) unsigned x_lds[T_ * F_ / 2];   // 32 KB packed f16 x
    __shared__ __align__(16) unsigned h0_p[2][H_ / 2];      // double-buffered h0 (f16 pairs)
    __shared__ __align__(16) unsigned h1_p[2][H_ / 2];      // double-buffered h1
    __shared__ __align__(16) unsigned wlin_p[512];          // w_lin packed f16 pairs
    __shared__ float blin_f[F_];

    const int tid   = threadIdx.x;
    const int b     = blockIdx.x;
    const int h_idx = tid >> 2;
    const int sub   = tid & 3;                          // quad lane == gate slot
    const int grow  = (0x3120 >> (sub * 4)) & 0xF;      // {0,2,1,3}[sub]
    const int row   = grow * H_ + h_idx;                // gate row (PyTorch i,f,g,o layout)

    // ---- stage x[b] into LDS as packed f16 pairs ----
    const float4* xp = (const float4*)(x + (size_t)b * T_ * F_);
    #pragma unroll
    for (int i = 0; i < 8; ++i) {
        int idx = tid + i * 512;          // 4096 float4 total
        float4 v = xp[idx];
        x_lds[idx * 2 + 0] = pk2h(v.x, v.y);
        x_lds[idx * 2 + 1] = pk2h(v.z, v.w);
    }

    // ---- per-thread full-row weights -> VGPRs/AGPRs (196 packed dwords) ----
    unsigned rwih0[4];
    {
        const float4* p = (const float4*)(wih0 + (size_t)row * F_);
        float4 v0 = p[0], v1 = p[1];
        rwih0[0] = pk2h(v0.x, v0.y); rwih0[1] = pk2h(v0.z, v0.w);
        rwih0[2] = pk2h(v1.x, v1.y); rwih0[3] = pk2h(v1.z, v1.w);
    }
    unsigned rwhh0[64], rwih1[64], rwhh1[64];
    {
        const float4* p = (const float4*)(whh0 + (size_t)row * H_);
        #pragma unroll
        for (int i = 0; i < 32; ++i) {
            float4 v = p[i];
            rwhh0[i * 2 + 0] = pk2h(v.x, v.y);
            rwhh0[i * 2 + 1] = pk2h(v.z, v.w);
        }
    }
    {
        const float4* p = (const float4*)(wih1 + (size_t)row * H_);
        #pragma unroll
        for (int i = 0; i < 32; ++i) {
            float4 v = p[i];
            rwih1[i * 2 + 0] = pk2h(v.x, v.y);
            rwih1[i * 2 + 1] = pk2h(v.z, v.w);
        }
    }
    {
        const float4* p = (const float4*)(whh1 + (size_t)row * H_);
        #pragma unroll
        for (int i = 0; i < 32; ++i) {
            float4 v = p[i];
            rwhh1[i * 2 + 0] = pk2h(v.x, v.y);
            rwhh1[i * 2 + 1] = pk2h(v.z, v.w);
        }
    }
    const float bias0 = bih0[row] + bhh0[row];
    const float bias1 = bih1[row] + bhh1[row];

    // w_lin: [8][128] fp32 -> 512 packed pairs; pair p = f*64 + k covers h = 2k,2k+1
    {
        float2 v = ((const float2*)wlin)[tid];
        wlin_p[tid] = pk2h(v.x, v.y);
    }
    if (tid < F_) blin_f[tid] = blin[tid];
    if (tid < H_ / 2) {
        h0_p[0][tid] = 0u; h0_p[1][tid] = 0u;
        h1_p[0][tid] = 0u; h1_p[1][tid] = 0u;
    }
    __syncthreads();

    const bool is_g = (sub == 1);
    const bool lo2  = (sub < 2);
    float c0 = 0.0f, c1 = 0.0f;    // cell state, replicated across each quad

    // t in [0, T]: tick t computes L0(t), L1(t); OUT(t-1) rides phase A.
    for (int t = 0; t <= T_; ++t) {
        const int rp = (t + 1) & 1;   // parity holding state(t-1)
        const int wp = t & 1;         // parity receiving state(t)

        // ---------- phase A: layer 0 at t (+ OUT(t-1) on wave 0) ----------
        if (t < T_) {
            float aa = bias0, ab = 0.0f;
            uint4 xv = *(const uint4*)&x_lds[t * 4];
            aa = fdot2a(rwih0[0], xv.x, aa);
            ab = fdot2a(rwih0[1], xv.y, ab);
            aa = fdot2a(rwih0[2], xv.z, aa);
            ab = fdot2a(rwih0[3], xv.w, ab);
            const unsigned* hr = &h0_p[rp][0];            // h0(t-1)
            #pragma unroll
            for (int j = 0; j < 16; ++j) {
                uint4 hv = *(const uint4*)&hr[j * 4];
                aa = fdot2a(rwhh0[j * 4 + 0], hv.x, aa);
                ab = fdot2a(rwhh0[j * 4 + 1], hv.y, ab);
                aa = fdot2a(rwhh0[j * 4 + 2], hv.z, aa);
                ab = fdot2a(rwhh0[j * 4 + 3], hv.w, ab);
            }
            float a = aa + ab;
            float xin = is_g ? 2.0f * a : a;
            float s   = sigm(xin);
            float act = is_g ? 2.0f * s - 1.0f : s;       // tanh via sigmoid, branch-free
            float s1  = lane_xor1(act);
            float p   = lo2 ? act * s1 : (sub == 2 ? act : s1) * c0;
            float cn  = p + lane_xor2(p);
            c0 = cn;
            float oval = (sub == 2) ? s1 : act;
            float h = oval * tanh_f(cn);
            if (sub == 2) ((_Float16*)&h0_p[wp][0])[h_idx] = (_Float16)h;  // h0(t)
        }

        // OUT(t-1): h1(t-1) sits in parity rp, stable through this whole tick.
        if (t >= 1 && tid < 64) {
            int fo = tid >> 3;       // output feature 0..7
            int l  = tid & 7;        // 8 lanes per feature, 16 h-elems each
            const unsigned* hp = &h1_p[rp][0];
            float a = 0.0f;
            #pragma unroll
            for (int jj = 0; jj < 8; ++jj) {
                a = fdot2a(wlin_p[fo * 64 + l * 8 + jj], hp[l * 8 + jj], a);
            }
            a += __shfl_down(a, 4, 8);
            a += __shfl_down(a, 2, 8);
            a += __shfl_down(a, 1, 8);
            if (l == 0) {
                out[((size_t)b * T_ + (t - 1)) * F_ + fo] = a + blin_f[fo];
            }
        }

        __syncthreads();   // h0(t) visible; also a scheduling/pressure fence

        // ---------- phase B: layer 1 at t (consumes fresh h0(t)) ----------
        if (t < T_) {
            float aa = bias1, ab = 0.0f, ba = 0.0f, bb = 0.0f;
            const unsigned* h0r = &h0_p[wp][0];   // h0(t)
            const unsigned* h1r = &h1_p[rp][0];   // h1(t-1)
            #pragma unroll
            for (int j = 0; j < 16; ++j) {
                uint4 hv0 = *(const uint4*)&h0r[j * 4];
                uint4 hv1 = *(const uint4*)&h1r[j * 4];
                aa = fdot2a(rwih1[j * 4 + 0], hv0.x, aa);
                ab = fdot2a(rwih1[j * 4 + 1], hv0.y, ab);
                aa = fdot2a(rwih1[j * 4 + 2], hv0.z, aa);
                ab = fdot2a(rwih1[j * 4 + 3], hv0.w, ab);
                ba = fdot2a(rwhh1[j * 4 + 0], hv1.x, ba);
                bb = fdot2a(rwhh1[j * 4 + 1], hv1.y, bb);
                ba = fdot2a(rwhh1[j * 4 + 2], hv1.z, ba);
                bb = fdot2a(rwhh1[j * 4 + 3], hv1.w, bb);
            }
            float a = (aa + ab) + (ba + bb);
            float xin = is_g ? 2.0f * a : a;
            float s   = sigm(xin);
            float act = is_g ? 2.0f * s - 1.0f : s;
            float s1  = lane_xor1(act);
            float p   = lo2 ? act * s1 : (sub == 2 ? act : s1) * c1;
            float cn  = p + lane_xor2(p);
            c1 = cn;
            float oval = (sub == 2) ? s1 : act;
            float h = oval * tanh_f(cn);
            if (sub == 2) ((_Float16*)&h1_p[wp][0])[h_idx] = (_Float16)h;  // h1(t)
        }

        __syncthreads();   // h1(t) visible; pressure fence
    }
}

extern "C" void kernel_launch(void* const* d_in, const int* in_sizes, int n_in,
                              void* d_out, int out_size, void* d_ws, size_t ws_size,
                              hipStream_t stream) {
    const float* x    = (const float*)d_in[0];
    const float* wih0 = (const float*)d_in[1];
    const float* whh0 = (const float*)d_in[2];
    const float* bih0 = (const float*)d_in[3];
    const float* bhh0 = (const float*)d_in[4];
    const float* wih1 = (const float*)d_in[5];
    const float* whh1 = (const float*)d_in[6];
    const float* bih1 = (const float*)d_in[7];
    const float* bhh1 = (const float*)d_in[8];
    const float* wlin = (const float*)d_in[9];
    const float* blin = (const float*)d_in[10];
    float* out = (float*)d_out;

    lstm2_2bar_kernel<<<dim3(B_), dim3(512), 0, stream>>>(
        x, wih0, whh0, bih0, bhh0, wih1, whh1, bih1, bhh1, wlin, blin, out);
}